// Round 11
// baseline (641.532 us; speedup 1.0000x reference)
//
#include <hip/hip_runtime.h>
#include <hip/hip_fp16.h>
#include <cstdint>
#include <cstddef>

#define BATCH 8
#define NN 2048
#define RTOT 16384   // BATCH*NN

// ---------------- workspace layout (offsets in floats) ----------------
static constexpr size_t OF_B1W   = 0;         // [30][64][2] = 3840
static constexpr size_t OF_B1B   = 3840;
static constexpr size_t OF_B2W   = 7680;
static constexpr size_t OF_B2B   = 11520;
static constexpr size_t OF_B3W   = 15360;     // [30][8][2] = 480
static constexpr size_t OF_B3B   = 15840;     // [100][8][2] = 1600
static constexpr size_t OF_S2    = 17440;     // [3][30][2] = 180
static constexpr size_t OF_CNT   = 17620;     // int barrier counter (+pad)
static constexpr size_t ZEND     = 17632;     // zero range [0, ZEND)
static constexpr size_t OF_DINVW = 17664;
static constexpr size_t OF_DINVB = OF_DINVW + 16384;          // 34048
// R18: ALL MFMA operands stored FRAGMENT-MAJOR [blk16][kb:64][lane:64][8].
// R19: k_build LDS-retiled coalesced A writes. R20/21: GEMMs 32-row blocks +
// deep unroll; R21 fixes pair grid (was 2x too many blocks -> OOB rows, NaN).
static constexpr size_t OF_HWBT  = OF_DINVB + 16384;          // 50432  fp16 frag [8][4cb][64][64][8]
static constexpr size_t OF_HW3T  = OF_HWBT + 524288;          // 574720 fp16 frag [8][2cb]...
static constexpr size_t OF_HBT   = OF_HW3T + 262144;          // 836864 fp16 frag [8][7cb]... (reused as S^T)
static constexpr size_t OF_ZW    = OF_HBT + 917504;           // 1754368 fp32 stride 32
static constexpr size_t OF_ZB    = OF_ZW + 524288;            // 2278656 fp32 stride 104 (reused as As)
static constexpr size_t OF_X11   = OF_ZB + 1703936;           // 3982592
static constexpr size_t OF_X12   = OF_X11 + 524288;
static constexpr size_t OF_X13   = OF_X12 + 524288;
static constexpr size_t OF_S11   = OF_X13 + 524288;
static constexpr size_t OF_S12   = OF_S11 + 524288;
static constexpr size_t OF_PARTMAX = OF_S12 + 524288;         // 6604032  256*90
static constexpr size_t OF_PP    = OF_PARTMAX + 23040;        // 6627072  256*13000
static constexpr size_t OF_PPOOL = OF_PP + 3328000;           // 9955072  8*13000
static constexpr size_t OF_AW    = OF_PPOOL + 104000;         // 10059072 fp16 frag [8][128rb][64][64][8]
static constexpr size_t OF_AB    = OF_AW + 16777216;          // 26836288
static constexpr size_t OF_SROW  = OF_AB + 16777216;          // 43613504 fp16 [RTOT][104] row-major S

typedef _Float16 f16x8 __attribute__((ext_vector_type(8)));
typedef float f32x4 __attribute__((ext_vector_type(4)));

#define FMA4(acc, s, h) { acc.x += (s)*(h).x; acc.y += (s)*(h).y; acc.z += (s)*(h).z; acc.w += (s)*(h).w; }

__device__ __forceinline__ unsigned short f2h(float f) {
  _Float16 h = (_Float16)f;
  return *(unsigned short*)&h;
}
__device__ __forceinline__ float h2f(unsigned short s) {
  _Float16 h = *(_Float16*)&s;
  return (float)h;
}

// fragment-major scalar index within one matrix: blk = (graphCB + col/16),
// element (col&15, k). Layout: [blk][kb:k>>5][kg:(k>>3)&3][lc:16][e:k&7]
__device__ __forceinline__ size_t fidx(size_t blk, int lc, int k) {
  return ((blk * 64 + (k >> 5)) * 64 + ((k >> 3) & 3) * 16 + lc) * 8 + (k & 7);
}

// ---------------- kernels ----------------

// R19: one 16-row frag rowblk per block (1024 blocks). Per 512-col chunk:
// coalesced 16x512 fp32 load -> LDS -> each thread emits 4 consecutive frag
// units (64B contiguous) for BOTH A matrices. Degrees fold into the load.
__global__ __launch_bounds__(256) void k_build(
    const float* __restrict__ adj, const float* __restrict__ x,
    const float* __restrict__ Win,
    _Float16* __restrict__ Aw, _Float16* __restrict__ Ab,
    float* __restrict__ dinvw, float* __restrict__ dinvb,
    _Float16* __restrict__ HT, float* __restrict__ zbase)
{
  __shared__ float tile[16*516];   // 33KB, pad 516 to spread banks
  __shared__ float dshw[16], dshb[16];
  int t = threadIdx.x;
  int blk = blockIdx.x;            // 1024 rowblks (= frag rowblk index)
  int r0 = blk << 4;
  size_t gph = (size_t)(r0 >> 11);
  if (blk < 69) {
    int zi = blk * 256 + t;
    if (zi < (int)ZEND) zbase[zi] = 0.f;
  }
  int lr = t >> 4, ls = t & 15;
  const float* rowp = adj + (size_t)(r0 + lr) * NN;
  float sum = 0.f; int cnt = 0;
  for (int ch = 0; ch < 4; ++ch) {
    int c0 = ch << 9;
    __syncthreads();
    const float4* rp = (const float4*)(rowp + c0);
#pragma unroll
    for (int i = 0; i < 8; ++i) {
      float4 v = rp[ls + (i << 4)];
      sum += v.x + v.y + v.z + v.w;
      cnt += (v.x != 0.f) + (v.y != 0.f) + (v.z != 0.f) + (v.w != 0.f);
      *(float4*)&tile[lr*516 + ls*4 + (i << 6)] = v;
    }
    __syncthreads();
    int kbG = (ch << 4) + lr;
    size_t base = (((size_t)blk * 4096) + (size_t)kbG * 64 + (size_t)ls * 4) * 8;
#pragma unroll
    for (int j = 0; j < 4; ++j) {
      int u = ls*4 + j;
      int kg = u >> 4, lc = u & 15;
      int crel = lr*32 + kg*8;
      const float* src = &tile[lc*516 + crel];
      int R = r0 + lc;
      int cg0 = c0 + crel;
      f16x8 wv, bv;
#pragma unroll
      for (int e = 0; e < 8; ++e) {
        float v = src[e];
        bool dg = (cg0 + e) == R;
        wv[e] = (_Float16)(dg ? 1.f : v);
        bv[e] = (_Float16)((dg || v != 0.f) ? 1.f : 0.f);
      }
      *(f16x8*)(Aw + base + j*8) = wv;
      *(f16x8*)(Ab + base + j*8) = bv;
    }
  }
#pragma unroll
  for (int o = 8; o; o >>= 1) { sum += __shfl_down(sum, o); cnt += __shfl_down(cnt, o); }
  if (ls == 0) {
    int R = r0 + lr;
    float dw = rsqrtf(sum + 1.f), db = rsqrtf((float)cnt + 1.f);
    dinvw[R] = dw; dinvb[R] = db;
    dshw[lr] = dw; dshb[lr] = db;
  }
  __syncthreads();
  {
    int R = r0 + lr, rloc = R & (NN-1);
    float x0 = x[R*3], x1 = x[R*3+1], x2 = x[R*3+2];
#pragma unroll
    for (int e = 0; e < 4; ++e) {
      int c = ls*4 + e;
      int side = c >> 5, cc = c & 31;
      float v = 0.f;
      if (cc < 30) {
        const float* W = Win + side*90;
        v = (x0*W[cc] + x1*W[30+cc] + x2*W[60+cc]) * (side ? dshb[lr] : dshw[lr]);
      }
      HT[fidx(gph*4 + (c >> 4), c & 15, rloc)] = (_Float16)v;
    }
  }
}

// R21: frag-major MFMA GEMM, levels 1,2. 1024 blocks: [0,512) weighted,
// [512,1024) binary; 32 rows each, 4 waves = (rowhalf x colhalf), 1 frag/wave,
// unroll 16. (R20 launched 2048 blocks -> rows past RTOT -> NaN.)
__global__ __launch_bounds__(256, 3) void k_gemm_pair(
    const _Float16* __restrict__ Aw, const _Float16* __restrict__ Ab,
    const _Float16* __restrict__ HT,
    const float* __restrict__ dinvw, const float* __restrict__ dinvb,
    float* __restrict__ Zw, float* __restrict__ Zb,
    float* __restrict__ bktW, float* __restrict__ bktB)
{
  __shared__ float zs[32][32];
  int t = threadIdx.x;
  int side = blockIdx.x >> 9;
  int rg = blockIdx.x & 511;
  int row0 = rg << 5;
  size_t g = (size_t)(row0 >> 11);
  int w = t >> 6, l = t & 63, lc = l & 15, kg = l >> 4;
  int rowhalf = w & 1, colhalf = w >> 1;
  const _Float16* A = side ? Ab : Aw;
  size_t rowblk = g*128 + ((row0 & 2047) >> 4) + rowhalf;
  const _Float16* Af = A  + (rowblk * 64) * 512 + l * 8;
  const _Float16* Bf = HT + (((size_t)(g*4 + side*2 + colhalf)) * 64) * 512 + l * 8;
  f32x4 acc = {0,0,0,0};
#pragma unroll 16
  for (int kb = 0; kb < 64; ++kb) {
    f16x8 af = *(const f16x8*)(Af + kb*512);
    f16x8 bf = *(const f16x8*)(Bf + kb*512);
    acc = __builtin_amdgcn_mfma_f32_16x16x32_f16(af, bf, acc, 0, 0, 0);
  }
#pragma unroll
  for (int i = 0; i < 4; ++i) zs[rowhalf*16 + kg*4 + i][colhalf*16 + lc] = acc[i];
  __syncthreads();
  {
    int r = t >> 3, c4 = (t & 7) << 2;
    float d = (side ? dinvb : dinvw)[row0 + r];
    float4 o;
    o.x = zs[r][c4+0] * d; o.y = zs[r][c4+1] * d;
    o.z = zs[r][c4+2] * d; o.w = zs[r][c4+3] * d;
    zs[r][c4+0] = o.x; zs[r][c4+1] = o.y; zs[r][c4+2] = o.z; zs[r][c4+3] = o.w;
    float* Zp = (side ? Zb : Zw) + (((size_t)(row0 + r)) << 5) + c4;
    *(float4*)Zp = o;
  }
  __syncthreads();
  int copy = blockIdx.x & 63;
  if (t < 30) {
    float s1 = 0.f, s2 = 0.f;
    for (int r = 0; r < 32; ++r) { float v = zs[r][t]; s1 += v; s2 += v*v; }
    float* bkt = side ? bktB : bktW;
    atomicAdd(&bkt[(t*64+copy)*2],   s1);
    atomicAdd(&bkt[(t*64+copy)*2+1], s2);
  }
}

// R20: frag-major level-3. Blocks [0,512): A_w @ Hw3 (32 rows, 1 frag/wave,
// unroll 16); [512,1024): A_b @ Hb100 (32 rows, waves = rowhalf x fraggroup).
__global__ __launch_bounds__(256, 3) void k_gemm_l3(
    const _Float16* __restrict__ Aw, const _Float16* __restrict__ Ab,
    const _Float16* __restrict__ Hw3T, const _Float16* __restrict__ HbT,
    const float* __restrict__ dinvw, const float* __restrict__ dinvb,
    float* __restrict__ Zw, float* __restrict__ Zb,
    float* __restrict__ bktW3, float* __restrict__ bktB3)
{
  __shared__ float zsst[1024];
  int t = threadIdx.x;
  int w = t >> 6, l = t & 63, lc = l & 15, kg = l >> 4;
  if (blockIdx.x < 512) {
    int row0 = blockIdx.x << 5;
    size_t g = (size_t)(row0 >> 11);
    int rowhalf = w & 1, colhalf = w >> 1;
    size_t rowblk = g*128 + ((row0 & 2047) >> 4) + rowhalf;
    const _Float16* Af = Aw   + (rowblk * 64) * 512 + l * 8;
    const _Float16* Bf = Hw3T + (((size_t)(g*2 + colhalf)) * 64) * 512 + l * 8;
    f32x4 acc = {0,0,0,0};
#pragma unroll 16
    for (int kb = 0; kb < 64; ++kb) {
      f16x8 af = *(const f16x8*)(Af + kb*512);
      f16x8 bf = *(const f16x8*)(Bf + kb*512);
      acc = __builtin_amdgcn_mfma_f32_16x16x32_f16(af, bf, acc, 0, 0, 0);
    }
    float (*zs)[32] = (float (*)[32])zsst;
#pragma unroll
    for (int i = 0; i < 4; ++i) zs[rowhalf*16 + kg*4 + i][colhalf*16 + lc] = acc[i];
    __syncthreads();
    {
      int r = t >> 3, c4 = (t & 7) << 2;
      float d = dinvw[row0 + r];
      float4 o;
      o.x = zs[r][c4+0] * d; o.y = zs[r][c4+1] * d;
      o.z = zs[r][c4+2] * d; o.w = zs[r][c4+3] * d;
      zs[r][c4+0] = o.x; zs[r][c4+1] = o.y; zs[r][c4+2] = o.z; zs[r][c4+3] = o.w;
      float* Zp = Zw + (((size_t)(row0 + r)) << 5) + c4;
      *(float4*)Zp = o;
    }
    __syncthreads();
    if (t < 30) {
      float s1 = 0.f, s2 = 0.f;
      for (int r = 0; r < 32; ++r) { float v = zs[r][t]; s1 += v; s2 += v*v; }
      int copy = blockIdx.x & 7;
      atomicAdd(&bktW3[(t*8+copy)*2],   s1);
      atomicAdd(&bktW3[(t*8+copy)*2+1], s2);
    }
  } else {
    int bid = blockIdx.x - 512;
    int row0 = bid << 5;
    size_t g = (size_t)(row0 >> 11);
    int rowhalf = w & 1, fgrp = w >> 1;       // fgrp 0: frags 0..3, 1: frags 4..6
    size_t rowblk = g*128 + ((row0 & 2047) >> 4) + rowhalf;
    const _Float16* Af = Ab + (rowblk * 64) * 512 + l * 8;
    for (int s = t; s < 200; s += 256) zsst[s] = 0.f;
    int f0 = fgrp * 4, nf = fgrp ? 3 : 4;
    const _Float16* Bf = HbT + (((size_t)(g*7 + f0)) * 64) * 512 + l * 8;
    f32x4 acc[4];
#pragma unroll
    for (int f = 0; f < 4; ++f) acc[f] = (f32x4){0,0,0,0};
    if (nf == 4) {
#pragma unroll 8
      for (int kb = 0; kb < 64; ++kb) {
        f16x8 af = *(const f16x8*)(Af + kb*512);
#pragma unroll
        for (int f = 0; f < 4; ++f) {
          f16x8 bf = *(const f16x8*)(Bf + (size_t)f*32768 + kb*512);
          acc[f] = __builtin_amdgcn_mfma_f32_16x16x32_f16(af, bf, acc[f], 0, 0, 0);
        }
      }
    } else {
#pragma unroll 8
      for (int kb = 0; kb < 64; ++kb) {
        f16x8 af = *(const f16x8*)(Af + kb*512);
#pragma unroll
        for (int f = 0; f < 3; ++f) {
          f16x8 bf = *(const f16x8*)(Bf + (size_t)f*32768 + kb*512);
          acc[f] = __builtin_amdgcn_mfma_f32_16x16x32_f16(af, bf, acc[f], 0, 0, 0);
        }
      }
    }
    __syncthreads();
    float d[4];
#pragma unroll
    for (int i = 0; i < 4; ++i) d[i] = dinvb[row0 + rowhalf*16 + kg*4 + i];
    for (int f = 0; f < nf; ++f) {
      int col = (f0 + f)*16 + lc;
#pragma unroll
      for (int i = 0; i < 4; ++i) {
        float v = acc[f][i] * d[i];
        int row = row0 + rowhalf*16 + kg*4 + i;
        if (col < 104) Zb[(size_t)row * 104 + col] = v;
        if (col < 100) { atomicAdd(&zsst[col*2], v); atomicAdd(&zsst[col*2+1], v*v); }
      }
    }
    __syncthreads();
    int copy = bid & 7;
    for (int i2 = t; i2 < 200; i2 += 256)
      atomicAdd(&bktB3[((i2>>1)*8 + copy)*2 + (i2&1)], zsst[i2]);
  }
}

// R20: frag-major As = adj @ S = A_w @ S - S. 512 blocks of 32 rows,
// waves = rowhalf x fraggroup.
__global__ __launch_bounds__(256, 3) void k_gemm_as(
    const _Float16* __restrict__ Aw, const _Float16* __restrict__ ST,
    const unsigned short* __restrict__ Srow, float* __restrict__ As)
{
  int t = threadIdx.x;
  int w = t >> 6, l = t & 63, lc = l & 15, kg = l >> 4;
  int row0 = blockIdx.x << 5;
  size_t g = (size_t)(row0 >> 11);
  int rowhalf = w & 1, fgrp = w >> 1;
  size_t rowblk = g*128 + ((row0 & 2047) >> 4) + rowhalf;
  const _Float16* Af = Aw + (rowblk * 64) * 512 + l * 8;
  int f0 = fgrp * 4, nf = fgrp ? 3 : 4;
  const _Float16* Bf = ST + (((size_t)(g*7 + f0)) * 64) * 512 + l * 8;
  f32x4 acc[4];
#pragma unroll
  for (int f = 0; f < 4; ++f) acc[f] = (f32x4){0,0,0,0};
  if (nf == 4) {
#pragma unroll 8
    for (int kb = 0; kb < 64; ++kb) {
      f16x8 af = *(const f16x8*)(Af + kb*512);
#pragma unroll
      for (int f = 0; f < 4; ++f) {
        f16x8 bf = *(const f16x8*)(Bf + (size_t)f*32768 + kb*512);
        acc[f] = __builtin_amdgcn_mfma_f32_16x16x32_f16(af, bf, acc[f], 0, 0, 0);
      }
    }
  } else {
#pragma unroll 8
    for (int kb = 0; kb < 64; ++kb) {
      f16x8 af = *(const f16x8*)(Af + kb*512);
#pragma unroll
      for (int f = 0; f < 3; ++f) {
        f16x8 bf = *(const f16x8*)(Bf + (size_t)f*32768 + kb*512);
        acc[f] = __builtin_amdgcn_mfma_f32_16x16x32_f16(af, bf, acc[f], 0, 0, 0);
      }
    }
  }
  for (int f = 0; f < nf; ++f) {
    int col = (f0 + f)*16 + lc;
#pragma unroll
    for (int i = 0; i < 4; ++i) {
      int row = row0 + rowhalf*16 + kg*4 + i;
      if (col < 104)
        As[(size_t)row * 104 + col] = acc[f][i] - h2f(Srow[(size_t)row * 104 + col]);
    }
  }
}

// apply BN (inline bucket reduce) -> store x/s -> next-layer weight GEMM ->
// fp16 frag-major H outputs.
template<int LEVEL>
__global__ __launch_bounds__(256) void k_apply_gemm(
    const float* __restrict__ Zw, const float* __restrict__ bktW,
    const float* __restrict__ gW, const float* __restrict__ beW,
    float* __restrict__ xst, const float* __restrict__ Ww,
    const float* __restrict__ dinvw,
    const float* __restrict__ Zb, const float* __restrict__ bktB,
    const float* __restrict__ gB, const float* __restrict__ beB,
    float* __restrict__ sst, const float* __restrict__ Wb,
    const float* __restrict__ dinvb,
    _Float16* __restrict__ HwOutT, _Float16* __restrict__ HbOutT)
{
  constexpr int NGB = (LEVEL == 1) ? 8 : 26;
  constexpr int OSTRIDEB = (LEVEL == 1) ? 32 : 104;
  constexpr int NG = 8 + NGB;
  __shared__ float WwL[30*32];
  __shared__ float WbL[30*OSTRIDEB];
  __shared__ float awL[60], abL[60];
  int t = threadIdx.x;
  if (t < 60) {
    int c = t % 30;
    bool isW = t < 30;
    const float4* p = (const float4*)((isW ? bktW : bktB) + c*128);
    float s1 = 0.f, s2 = 0.f;
#pragma unroll
    for (int k = 0; k < 32; ++k) { float4 v = p[k]; s1 += v.x + v.z; s2 += v.y + v.w; }
    float mean = s1/16384.f, var = s2/16384.f - mean*mean, inv = rsqrtf(var + 1e-5f);
    float aa = (isW ? gW : gB)[c]*inv;
    float* dst = isW ? awL : abL;
    dst[c] = aa; dst[30+c] = (isW ? beW : beB)[c] - mean*aa;
  }
  for (int idx = t; idx < 30*32; idx += 256) {
    int k = idx >> 5, c = idx & 31;
    WwL[idx] = (c < 30) ? Ww[k*30 + c] : 0.f;
  }
  if (LEVEL == 1) {
    for (int idx = t; idx < 30*32; idx += 256) {
      int k = idx >> 5, c = idx & 31;
      WbL[idx] = (c < 30) ? Wb[k*30 + c] : 0.f;
    }
  } else {
    for (int idx = t; idx < 30*OSTRIDEB; idx += 256) {
      int k = idx / OSTRIDEB, j = idx % OSTRIDEB;
      WbL[idx] = (j < 100) ? Wb[k*100 + j] : 0.f;
    }
  }
  __syncthreads();
  int gid = blockIdx.x * 256 + t;
  int row = gid / NG, g = gid % NG;
  size_t gph = (size_t)(row >> 11);
  int rloc = row & (NN-1);
  if (g < 8) {
    const float4* Z4 = (const float4*)Zw + (size_t)row*8;
    float4 z4[8];
#pragma unroll
    for (int u = 0; u < 8; ++u) z4[u] = Z4[u];
    const float* z = (const float*)z4;
    int ch = 4*g;
    float4 zg = Z4[g];
    float4 xv;
    xv.x = (ch+0 < 30) ? awL[ch+0]*zg.x + awL[30+ch+0] : 0.f;
    xv.y = (ch+1 < 30) ? awL[ch+1]*zg.y + awL[30+ch+1] : 0.f;
    xv.z = (ch+2 < 30) ? awL[ch+2]*zg.z + awL[30+ch+2] : 0.f;
    xv.w = (ch+3 < 30) ? awL[ch+3]*zg.w + awL[30+ch+3] : 0.f;
    ((float4*)xst)[(size_t)row*8+g] = xv;
    float4 o = {0,0,0,0};
#pragma unroll
    for (int k = 0; k < 30; ++k) {
      float xk = awL[k]*z[k] + awL[30+k];
      float4 w = *(const float4*)(WwL + k*32 + 4*g);
      FMA4(o, xk, w);
    }
    float d = dinvw[row];
    float ov[4] = {d*o.x, d*o.y, d*o.z, d*o.w};
#pragma unroll
    for (int i = 0; i < 4; ++i) {
      int col = ch + i;
      if (LEVEL == 1) HwOutT[fidx(gph*4 + (col>>4), col & 15, rloc)] = (_Float16)ov[i];
      else            HwOutT[fidx(gph*2 + (col>>4), col & 15, rloc)] = (_Float16)ov[i];
    }
  } else {
    int gb = g - 8;
    const float4* Z4 = (const float4*)Zb + (size_t)row*8;
    float4 z4[8];
#pragma unroll
    for (int u = 0; u < 8; ++u) z4[u] = Z4[u];
    const float* z = (const float*)z4;
    if (gb < 8) {
      int ch = 4*gb;
      float4 zg = Z4[gb];
      float4 sv;
      sv.x = (ch+0 < 30) ? abL[ch+0]*zg.x + abL[30+ch+0] : 0.f;
      sv.y = (ch+1 < 30) ? abL[ch+1]*zg.y + abL[30+ch+1] : 0.f;
      sv.z = (ch+2 < 30) ? abL[ch+2]*zg.z + abL[30+ch+2] : 0.f;
      sv.w = (ch+3 < 30) ? abL[ch+3]*zg.w + abL[30+ch+3] : 0.f;
      ((float4*)sst)[(size_t)row*8+gb] = sv;
    }
    float4 o = {0,0,0,0};
#pragma unroll
    for (int k = 0; k < 30; ++k) {
      float sk = abL[k]*z[k] + abL[30+k];
      float4 w = *(const float4*)(WbL + k*OSTRIDEB + 4*gb);
      FMA4(o, sk, w);
    }
    float d = dinvb[row];
    float ov[4] = {d*o.x, d*o.y, d*o.z, d*o.w};
#pragma unroll
    for (int i = 0; i < 4; ++i) {
      int col = 4*gb + i;
      if (LEVEL == 1) { int c2 = 32 + col; HbOutT[fidx(gph*4 + (c2>>4), c2 & 15, rloc)] = (_Float16)ov[i]; }
      else            HbOutT[fidx(gph*7 + (col>>4), col & 15, rloc)] = (_Float16)ov[i];
    }
    if (LEVEL == 2) {
      if (gb == 24) {
#pragma unroll
        for (int c = 104; c < 108; ++c) HbOutT[fidx(gph*7 + 6, c & 15, rloc)] = (_Float16)0.f;
      } else if (gb == 25) {
#pragma unroll
        for (int c = 108; c < 112; ++c) HbOutT[fidx(gph*7 + 6, c & 15, rloc)] = (_Float16)0.f;
      }
    }
  }
}

// fcpool with inline L3 finalize + fused softmax -> S row-major [row][104] AND
// frag-major S^T (B-operand for the As GEMM; pad cols zeroed).
__global__ __launch_bounds__(256) void k_fcpool(
    const float* __restrict__ Zw3, const float* __restrict__ bktW3,
    const float* __restrict__ gW3, const float* __restrict__ beW3,
    const float* __restrict__ Zb3, const float* __restrict__ bktB3,
    const float* __restrict__ g100, const float* __restrict__ be100,
    const float* __restrict__ s11, const float* __restrict__ s12,
    const float* __restrict__ Wfc, const float* __restrict__ bfc,
    float* __restrict__ x13, unsigned short* __restrict__ Srow,
    _Float16* __restrict__ ST)
{
  __shared__ float shm[14240];   // feat 64x160 = 10240 | Wl 40x100 = 4000
  __shared__ float aw3[60], ab3[200];
  float* feat = shm;
  float* Wl = shm + 10240;
  int t = threadIdx.x;
  int g0 = blockIdx.x * 64;
  size_t gph = (size_t)(g0 >> 11);
  if (t < 30) {
    const float4* p = (const float4*)(bktW3 + t*16);
    float s1 = 0.f, s2 = 0.f;
#pragma unroll
    for (int k = 0; k < 4; ++k) { float4 v = p[k]; s1 += v.x + v.z; s2 += v.y + v.w; }
    float mean = s1/16384.f, var = s2/16384.f - mean*mean, inv = rsqrtf(var + 1e-5f);
    float aa = gW3[t]*inv; aw3[t] = aa; aw3[30+t] = beW3[t] - mean*aa;
  } else if (t >= 64 && t < 164) {
    int c = t - 64;
    const float4* p = (const float4*)(bktB3 + c*16);
    float s1 = 0.f, s2 = 0.f;
#pragma unroll
    for (int k = 0; k < 4; ++k) { float4 v = p[k]; s1 += v.x + v.z; s2 += v.y + v.w; }
    float mean = s1/16384.f, var = s2/16384.f - mean*mean, inv = rsqrtf(var + 1e-5f);
    float aa = g100[c]*inv; ab3[c] = aa; ab3[100+c] = be100[c] - mean*aa;
  }
  __syncthreads();
  for (int idx = t; idx < 64*160; idx += 256) {
    int l = idx / 160, c = idx % 160;
    int g = g0 + l;
    float v;
    if (c < 30) v = s11[(size_t)g*32 + c];
    else if (c < 60) v = s12[(size_t)g*32 + (c-30)];
    else { int k = c - 60; v = ab3[k]*Zb3[(size_t)g*104 + k] + ab3[100 + k]; }
    feat[l*160 + c] = v;
  }
  for (int idx = t; idx < 64*32; idx += 256) {
    int l = idx >> 5, c = idx & 31;
    int g = g0 + l;
    x13[(size_t)g*32+c] = (c < 30) ? aw3[c]*Zw3[(size_t)g*32+c] + aw3[30+c] : 0.f;
  }
  int np = t >> 3, kg = t & 7;
  int n0 = np*2, n1 = np*2 + 1;
  int kbase = kg*12 + (kg < 4 ? kg : 4);
  int klen  = kg < 4 ? 13 : 12;
  float a0[13], a1[13];
#pragma unroll
  for (int j = 0; j < 13; ++j) { a0[j] = 0.f; a1[j] = 0.f; }
  for (int ch = 0; ch < 4; ++ch) {
    __syncthreads();
    for (int idx = t; idx < 4000; idx += 256) {
      int r = idx/100, j = idx%100;
      Wl[r*100 + j] = Wfc[(ch*40 + r)*100 + j];
    }
    __syncthreads();
    for (int kk = 0; kk < 40; ++kk) {
      float f0 = feat[n0*160 + ch*40+kk];
      float f1 = feat[n1*160 + ch*40+kk];
#pragma unroll
      for (int j = 0; j < 13; ++j) {
        if (j < klen) {
          float w = Wl[kk*100 + kbase + j];
          a0[j] += f0*w; a1[j] += f1*w;
        }
      }
    }
  }
  __syncthreads();
  float* sRow = shm;  // reuse as [64][100]
  for (int j = 0; j < klen; ++j) {
    int k = kbase + j;
    sRow[n0*100 + k] = a0[j] + bfc[k];
    sRow[n1*100 + k] = a1[j] + bfc[k];
  }
  __syncthreads();
  int n = t >> 2, part = t & 3;
  int i0 = part*25;
  int rloc = (g0 + n) & (NN-1);
  float m = -3.4e38f;
  for (int i = 0; i < 25; ++i) m = fmaxf(m, sRow[n*100 + i0 + i]);
  m = fmaxf(m, __shfl_xor(m, 1));
  m = fmaxf(m, __shfl_xor(m, 2));
  float ev[25]; float s = 0.f;
  for (int i = 0; i < 25; ++i) { float e = __expf(sRow[n*100 + i0 + i] - m); ev[i] = e; s += e; }
  s += __shfl_xor(s, 1);
  s += __shfl_xor(s, 2);
  float rinv = 1.f / s;
  for (int i = 0; i < 25; ++i) {
    float v = ev[i] * rinv;
    int c = i0 + i;
    Srow[(size_t)(g0+n)*104 + c] = f2h(v);
    ST[fidx(gph*7 + (c>>4), c & 15, rloc)] = (_Float16)v;
  }
  if (part == 3) {
#pragma unroll
    for (int c = 100; c < 104; ++c) Srow[(size_t)(g0+n)*104 + c] = 0;
#pragma unroll
    for (int c = 100; c < 112; ++c) ST[fidx(gph*7 + (c>>4), c & 15, rloc)] = (_Float16)0.f;
  }
}

// pooled partials + FUSED stage-1 column max (256 blocks, one 64-row tile each).
__global__ __launch_bounds__(256) void k_pool_part(
    const unsigned short* __restrict__ S, const float* __restrict__ x13,
    const float* __restrict__ As, const float* __restrict__ x11,
    const float* __restrict__ x12, float* __restrict__ pp, float* __restrict__ pm)
{
  __shared__ float sL[64][100];
  __shared__ float xL[64][132];
  __shared__ float red[256];
  int t = threadIdx.x;
  int b = blockIdx.x >> 5, chunk = blockIdx.x & 31;
  int g0 = b * 2048 + chunk * 64;
  int kt = t/10, dt = t%10;
  int k0 = kt*4, d0 = dt*13;
  float acc[4][13];
#pragma unroll
  for (int a = 0; a < 4; ++a)
#pragma unroll
    for (int j = 0; j < 13; ++j) acc[a][j] = 0.f;
  for (int idx = t; idx < 64*100; idx += 256) {
    int l = idx/100, k = idx%100;
    sL[l][k] = h2f(S[(size_t)(g0+l)*104 + k]);
  }
  for (int idx = t; idx < 64*130; idx += 256) {
    int l = idx/130, d = idx%130;
    xL[l][d] = d < 30 ? x13[(size_t)(g0+l)*32 + d] : As[(size_t)(g0+l)*104 + (d-30)];
  }
  __syncthreads();
  if (t < 250) {
    for (int kk = 0; kk < 64; ++kk) {
      float sv[4];
#pragma unroll
      for (int a = 0; a < 4; ++a) sv[a] = sL[kk][k0+a];
#pragma unroll
      for (int j = 0; j < 13; ++j) {
        float xv = xL[kk][d0+j];
#pragma unroll
        for (int a = 0; a < 4; ++a) acc[a][j] += sv[a]*xv;
      }
    }
    float* dst = pp + (size_t)blockIdx.x * 13000;
    for (int a = 0; a < 4; ++a)
      for (int j = 0; j < 13; ++j)
        dst[(k0+a)*130 + (d0+j)] = acc[a][j];
  }
  __syncthreads();
  {
    int c = t & 31, rg = t >> 5;
    const float* srcs[3] = {x11, x12, x13};
#pragma unroll
    for (int a = 0; a < 3; ++a) {
      const float* p = srcs[a] + (size_t)(g0+rg)*32 + c;
      float m = -3.4e38f;
#pragma unroll
      for (int it = 0; it < 8; ++it) m = fmaxf(m, p[it*256]);
      red[t] = m;
      __syncthreads();
      if (t < 30) {
        float mm = red[t];
        for (int g = 1; g < 8; ++g) mm = fmaxf(mm, red[g*32+t]);
        pm[(size_t)blockIdx.x*90 + a*30 + t] = mm;
      }
      __syncthreads();
    }
  }
}

// full-GPU reduction of the 32 pool partials per graph -> ppool[8][13000].
__global__ __launch_bounds__(256) void k_pool_reduce(
    const float* __restrict__ pp, float* __restrict__ ppool)
{
  int b = blockIdx.x / 51, blk = blockIdx.x % 51;
  int idx = blk * 256 + threadIdx.x;
  if (idx < 13000) {
    const float* src = pp + (size_t)b * 32 * 13000 + idx;
    float s = 0.f;
#pragma unroll
    for (int c = 0; c < 32; ++c) s += src[c*13000];
    ppool[(size_t)b*13000 + idx] = s;
  }
}

// Fully fused stage 2 (register-tiled, fp32 A2 in LDS).
__global__ __launch_bounds__(256) void k_s2fused(
    const float* __restrict__ ppool, const float* __restrict__ partmax,
    const float* __restrict__ Wm,    // 3 consecutive 30x30
    const float* __restrict__ g30,   // +150
    const float* __restrict__ be30,  // +150
    float* __restrict__ bktS2,       // [3][30][2] (zeroed)
    int* __restrict__ cnt,           // zeroed barrier counter
    const float* __restrict__ W1, const float* __restrict__ b1,
    const float* __restrict__ W2, const float* __restrict__ b2,
    float* __restrict__ out)
{
  __shared__ float A2f[10000];     // 40 KB, fp32
  __shared__ float buf1[3000];     // X (stride 30)
  __shared__ float buf2[3200];     // T padded [100][32]
  __shared__ float WL[960];        // W padded [30][32]
  __shared__ float dl[100];
  __shared__ float st1[30], st2[30];
  __shared__ float coef[60];
  __shared__ float x1L[90], x2L[90], hh[50];
  int b = blockIdx.x, t = threadIdx.x;
  for (int idx = t; idx < 13000; idx += 256) {
    float s = ppool[(size_t)b*13000 + idx];
    int k = idx/130, d = idx%130;
    if (d < 30) buf1[k*30 + d] = s;
    else A2f[k*100 + (d-30)] = s;
  }
  __syncthreads();
  if (t < 100 && A2f[t*101] == 0.f) A2f[t*101] = 1.f;
  __syncthreads();
  if (t < 100) {
    float s = 0.f;
    for (int j = 0; j < 100; ++j) s += A2f[t*100 + j];
    dl[t] = s > 0.f ? rsqrtf(s) : 0.f;
  }
  __syncthreads();
  for (int idx = t; idx < 10000; idx += 256) {
    int i = idx/100, j = idx%100;
    A2f[idx] = dl[i]*dl[j]*A2f[idx];
  }
  int rp = t >> 2, cg = t & 3;
  int i0 = rp*2, c0 = cg*8;
  bool act = (t < 200);
  for (int L = 0; L < 3; ++L) {
    if (t < 30) { st1[t] = 0.f; st2[t] = 0.f; }
    const float* W = Wm + L*900;
    for (int idx = t; idx < 960; idx += 256) {
      int k = idx >> 5, c = idx & 31;
      WL[idx] = (c < 30) ? W[k*30 + c] : 0.f;
    }
    __syncthreads();
    if (act) {
      float a0[8] = {0,0,0,0,0,0,0,0}, a1[8] = {0,0,0,0,0,0,0,0};
      for (int k = 0; k < 30; ++k) {
        float xx0 = buf1[i0*30 + k], xx1 = buf1[(i0+1)*30 + k];
        float4 w0 = *(const float4*)&WL[k*32 + c0];
        float4 w1 = *(const float4*)&WL[k*32 + c0 + 4];
        a0[0] += xx0*w0.x; a0[1] += xx0*w0.y; a0[2] += xx0*w0.z; a0[3] += xx0*w0.w;
        a0[4] += xx0*w1.x; a0[5] += xx0*w1.y; a0[6] += xx0*w1.z; a0[7] += xx0*w1.w;
        a1[0] += xx1*w0.x; a1[1] += xx1*w0.y; a1[2] += xx1*w0.z; a1[3] += xx1*w0.w;
        a1[4] += xx1*w1.x; a1[5] += xx1*w1.y; a1[6] += xx1*w1.z; a1[7] += xx1*w1.w;
      }
      float4 s00 = {a0[0],a0[1],a0[2],a0[3]}, s01 = {a0[4],a0[5],a0[6],a0[7]};
      float4 s10 = {a1[0],a1[1],a1[2],a1[3]}, s11v = {a1[4],a1[5],a1[6],a1[7]};
      *(float4*)&buf2[i0*32 + c0]       = s00;
      *(float4*)&buf2[i0*32 + c0 + 4]   = s01;
      *(float4*)&buf2[(i0+1)*32 + c0]   = s10;
      *(float4*)&buf2[(i0+1)*32 + c0+4] = s11v;
    }
    __syncthreads();
    if (act) {
      float z0[8] = {0,0,0,0,0,0,0,0}, z1[8] = {0,0,0,0,0,0,0,0};
      for (int j = 0; j < 100; ++j) {
        float av0 = A2f[i0*100 + j], av1 = A2f[(i0+1)*100 + j];
        float4 t0 = *(const float4*)&buf2[j*32 + c0];
        float4 t1 = *(const float4*)&buf2[j*32 + c0 + 4];
        z0[0] += av0*t0.x; z0[1] += av0*t0.y; z0[2] += av0*t0.z; z0[3] += av0*t0.w;
        z0[4] += av0*t1.x; z0[5] += av0*t1.y; z0[6] += av0*t1.z; z0[7] += av0*t1.w;
        z1[0] += av1*t0.x; z1[1] += av1*t0.y; z1[2] += av1*t0.z; z1[3] += av1*t0.w;
        z1[4] += av1*t1.x; z1[5] += av1*t1.y; z1[6] += av1*t1.z; z1[7] += av1*t1.w;
      }
#pragma unroll
      for (int k = 0; k < 8; ++k) {
        int c = c0 + k;
        if (c < 30) {
          buf1[i0*30 + c]     = z0[k];
          buf1[(i0+1)*30 + c] = z1[k];
          atomicAdd(&st1[c], z0[k] + z1[k]);
          atomicAdd(&st2[c], z0[k]*z0[k] + z1[k]*z1[k]);
        }
      }
    }
    __syncthreads();
    if (t < 30) {
      atomicAdd(&bktS2[(L*30+t)*2],   st1[t]);
      atomicAdd(&bktS2[(L*30+t)*2+1], st2[t]);
    }
    __syncthreads();
    if (t == 0) {
      __threadfence();
      atomicAdd(cnt, 1);
      while (atomicAdd(cnt, 0) < (L+1)*8) {}
      __threadfence();
    }
    __syncthreads();
    if (t < 30) {
      float s1 = atomicAdd(&bktS2[(L*30+t)*2],   0.f);
      float s2 = atomicAdd(&bktS2[(L*30+t)*2+1], 0.f);
      float mean = s1/800.f, var = s2/800.f - mean*mean, inv = rsqrtf(var + 1e-5f);
      float aa = g30[L*30+t]*inv;
      coef[t] = aa; coef[30+t] = be30[L*30+t] - mean*aa;
    }
    __syncthreads();
    if (L < 2) {
      for (int idx = t; idx < 3000; idx += 256) {
        int c = idx % 30;
        buf1[idx] = coef[c]*buf1[idx] + coef[30+c];
      }
      __syncthreads();
      if (t < 30) {
        float m = -3.4e38f;
        for (int i = 0; i < 100; ++i) m = fmaxf(m, buf1[i*30+t]);
        x2L[L*30+t] = m;
      }
      __syncthreads();
    } else {
      if (t < 30) {
        float m = -3.4e38f;
        for (int i = 0; i < 100; ++i) m = fmaxf(m, coef[t]*buf1[i*30+t] + coef[30+t]);
        x2L[60+t] = m;
      }
    }
  }
  if (t < 90) {
    float m = -3.4e38f;
    for (int s = 0; s < 32; ++s) m = fmaxf(m, partmax[(size_t)(b*32+s)*90 + t]);
    x1L[t] = m;
  }
  __syncthreads();
  if (t < 50) {
    float a = b1[t];
    for (int k = 0; k < 90; ++k) a += x1L[k]*W1[k*50+t];
    for (int k = 0; k < 90; ++k) a += x2L[k]*W1[(90+k)*50+t];
    hh[t] = fmaxf(a, 0.f);
  }
  __syncthreads();
  if (t < 6) {
    float a = b2[t];
    for (int j = 0; j < 50; ++j) a += hh[j]*W2[j*6+t];
    out[b*6+t] = a;
  }
}

// ---------------- launcher ----------------
extern "C" void kernel_launch(void* const* d_in, const int* in_sizes, int n_in,
                              void* d_out, int out_size, void* d_ws, size_t ws_size,
                              hipStream_t stream)
{
  const float* x    = (const float*)d_in[0];
  const float* adj  = (const float*)d_in[1];
  const float* Win  = (const float*)d_in[2];
  const float* W3030= (const float*)d_in[3];
  const float* Wp13 = (const float*)d_in[4];
  // d_in[5]=b30, d_in[6]=b100: cancel through training-mode BN -> unused
  const float* Wfc  = (const float*)d_in[7];
  const float* bfc  = (const float*)d_in[8];
  const float* W1   = (const float*)d_in[9];
  const float* b1   = (const float*)d_in[10];
  const float* W2   = (const float*)d_in[11];
  const float* b2   = (const float*)d_in[12];
  const float* g30  = (const float*)d_in[13];
  const float* be30 = (const float*)d_in[14];
  const float* g100 = (const float*)d_in[15];
  const float* be100= (const float*)d_in[16];
  float* out = (float*)d_out;

  float* wsf = (float*)d_ws;
  float* bL1W = wsf + OF_B1W;  float* bL1B = wsf + OF_B1B;
  float* bL2W = wsf + OF_B2W;  float* bL2B = wsf + OF_B2B;
  float* bL3W = wsf + OF_B3W;  float* bL3B = wsf + OF_B3B;
  float* bktS2 = wsf + OF_S2;
  int*   cnt  = (int*)(wsf + OF_CNT);
  float* dinvw = wsf + OF_DINVW;
  float* dinvb = wsf + OF_DINVB;
  _Float16* HwbT = (_Float16*)(wsf + OF_HWBT);
  _Float16* Hw3T = (_Float16*)(wsf + OF_HW3T);
  _Float16* HbT  = (_Float16*)(wsf + OF_HBT);   // S^T reuses (dead after l3)
  float* Zw = wsf + OF_ZW;
  float* Zb = wsf + OF_ZB;         // stride 104; later reused as As
  float* x11 = wsf + OF_X11;
  float* x12 = wsf + OF_X12;
  float* x13 = wsf + OF_X13;
  float* s11 = wsf + OF_S11;
  float* s12 = wsf + OF_S12;
  float* pp  = wsf + OF_PP;        // [256][13000] pool partials
  float* ppool = wsf + OF_PPOOL;   // [8][13000] reduced
  float* partmax = wsf + OF_PARTMAX; // [256][90]
  _Float16* Aw = (_Float16*)(wsf + OF_AW);
  _Float16* Ab = (_Float16*)(wsf + OF_AB);
  unsigned short* Srow = (unsigned short*)(wsf + OF_SROW);

  // 11 dispatches
  k_build<<<1024, 256, 0, stream>>>(adj, x, Win, Aw, Ab, dinvw, dinvb, HwbT, wsf);

  k_gemm_pair<<<1024, 256, 0, stream>>>(Aw, Ab, HwbT, dinvw, dinvb, Zw, Zb, bL1W, bL1B);
  k_apply_gemm<1><<<1024, 256, 0, stream>>>(Zw, bL1W, g30+0, be30+0, x11, W3030+0, dinvw,
                                            Zb, bL1B, g30+90, be30+90, s11, W3030+2*900, dinvb, HwbT, HwbT);

  k_gemm_pair<<<1024, 256, 0, stream>>>(Aw, Ab, HwbT, dinvw, dinvb, Zw, Zb, bL2W, bL2B);
  k_apply_gemm<2><<<2176, 256, 0, stream>>>(Zw, bL2W, g30+30, be30+30, x12, W3030+900, dinvw,
                                            Zb, bL2B, g30+120, be30+120, s12, Wp13, dinvb, Hw3T, HbT);

  k_gemm_l3<<<1024, 256, 0, stream>>>(Aw, Ab, Hw3T, HbT, dinvw, dinvb, Zw, Zb, bL3W, bL3B);
  k_fcpool<<<256, 256, 0, stream>>>(Zw, bL3W, g30+60, be30+60, Zb, bL3B, g100, be100,
                                    s11, s12, Wfc, bfc, x13, Srow, HbT /* S^T */);

  k_gemm_as<<<512, 256, 0, stream>>>(Aw, HbT /* S^T */, Srow, Zb /* As */);
  k_pool_part<<<256, 256, 0, stream>>>(Srow, x13, Zb, x11, x12, pp, partmax);
  k_pool_reduce<<<408, 256, 0, stream>>>(pp, ppool);

  k_s2fused<<<BATCH, 256, 0, stream>>>(ppool, partmax, W3030+3*900, g30+150, be30+150,
                                       bktS2, cnt, W1, b1, W2, b2, out);
}

// Round 12
// 593.439 us; speedup vs baseline: 1.0810x; 1.0810x over previous
//
#include <hip/hip_runtime.h>
#include <hip/hip_fp16.h>
#include <cstdint>
#include <cstddef>

#define BATCH 8
#define NN 2048
#define RTOT 16384   // BATCH*NN

// ---------------- workspace layout (offsets in floats) ----------------
static constexpr size_t OF_B1W   = 0;         // [30][64][2] = 3840
static constexpr size_t OF_B1B   = 3840;
static constexpr size_t OF_B2W   = 7680;
static constexpr size_t OF_B2B   = 11520;
static constexpr size_t OF_B3W   = 15360;     // [30][8][2] = 480
static constexpr size_t OF_B3B   = 15840;     // [100][8][2] = 1600
static constexpr size_t OF_S2    = 17440;     // [3][30][2] = 180
static constexpr size_t OF_CNT   = 17620;     // int barrier counter (+pad)
static constexpr size_t ZEND     = 17632;     // zero range [0, ZEND)
static constexpr size_t OF_DINVW = 17664;
static constexpr size_t OF_DINVB = OF_DINVW + 16384;          // 34048
// R18: frag-major operands. R19: coalesced build. R22: Ab never materialized —
// binary A derived in-register from Aw (halves GEMM A-traffic + build writes).
static constexpr size_t OF_HWBT  = OF_DINVB + 16384;          // 50432  fp16 frag [8][4cb][64][64][8]
static constexpr size_t OF_HW3T  = OF_HWBT + 524288;          // 574720 fp16 frag [8][2cb]...
static constexpr size_t OF_HBT   = OF_HW3T + 262144;          // 836864 fp16 frag [8][7cb]... (reused as S^T)
static constexpr size_t OF_ZW    = OF_HBT + 917504;           // 1754368 fp32 stride 32
static constexpr size_t OF_ZB    = OF_ZW + 524288;            // 2278656 fp32 stride 104 (reused as As)
static constexpr size_t OF_X11   = OF_ZB + 1703936;           // 3982592
static constexpr size_t OF_X12   = OF_X11 + 524288;
static constexpr size_t OF_X13   = OF_X12 + 524288;
static constexpr size_t OF_S11   = OF_X13 + 524288;
static constexpr size_t OF_S12   = OF_S11 + 524288;
static constexpr size_t OF_PARTMAX = OF_S12 + 524288;         // 6604032  256*90
static constexpr size_t OF_PP    = OF_PARTMAX + 23040;        // 6627072  256*13000
static constexpr size_t OF_PPOOL = OF_PP + 3328000;           // 9955072  8*13000
static constexpr size_t OF_AW    = OF_PPOOL + 104000;         // 10059072 fp16 frag [8][128rb][64][64][8]
static constexpr size_t OF_SROW  = OF_AW + 16777216;          // 26836288 fp16 [RTOT][104] row-major S

typedef _Float16 f16x8 __attribute__((ext_vector_type(8)));
typedef float f32x4 __attribute__((ext_vector_type(4)));

#define FMA4(acc, s, h) { acc.x += (s)*(h).x; acc.y += (s)*(h).y; acc.z += (s)*(h).z; acc.w += (s)*(h).w; }

__device__ __forceinline__ unsigned short f2h(float f) {
  _Float16 h = (_Float16)f;
  return *(unsigned short*)&h;
}
__device__ __forceinline__ float h2f(unsigned short s) {
  _Float16 h = *(_Float16*)&s;
  return (float)h;
}

// binary A fragment from weighted A fragment (diag already 1 in both)
__device__ __forceinline__ f16x8 binz(f16x8 a) {
  f16x8 r;
#pragma unroll
  for (int e = 0; e < 8; ++e) r[e] = (a[e] != (_Float16)0.f) ? (_Float16)1.f : (_Float16)0.f;
  return r;
}

// fragment-major scalar index: [blk][kb:k>>5][kg:(k>>3)&3][lc:16][e:k&7]
__device__ __forceinline__ size_t fidx(size_t blk, int lc, int k) {
  return ((blk * 64 + (k >> 5)) * 64 + ((k >> 3) & 3) * 16 + lc) * 8 + (k & 7);
}

// ---------------- kernels ----------------

// R19/R22: one 16-row frag rowblk per block. Coalesced 16x512 fp32 load -> LDS
// -> coalesced frag emit for Aw ONLY (Ab derived in-register by consumers).
__global__ __launch_bounds__(256) void k_build(
    const float* __restrict__ adj, const float* __restrict__ x,
    const float* __restrict__ Win,
    _Float16* __restrict__ Aw,
    float* __restrict__ dinvw, float* __restrict__ dinvb,
    _Float16* __restrict__ HT, float* __restrict__ zbase)
{
  __shared__ float tile[16*516];   // 33KB, pad 516 to spread banks
  __shared__ float dshw[16], dshb[16];
  int t = threadIdx.x;
  int blk = blockIdx.x;            // 1024 rowblks
  int r0 = blk << 4;
  size_t gph = (size_t)(r0 >> 11);
  if (blk < 69) {
    int zi = blk * 256 + t;
    if (zi < (int)ZEND) zbase[zi] = 0.f;
  }
  int lr = t >> 4, ls = t & 15;
  const float* rowp = adj + (size_t)(r0 + lr) * NN;
  float sum = 0.f; int cnt = 0;
  for (int ch = 0; ch < 4; ++ch) {
    int c0 = ch << 9;
    __syncthreads();
    const float4* rp = (const float4*)(rowp + c0);
#pragma unroll
    for (int i = 0; i < 8; ++i) {
      float4 v = rp[ls + (i << 4)];
      sum += v.x + v.y + v.z + v.w;
      cnt += (v.x != 0.f) + (v.y != 0.f) + (v.z != 0.f) + (v.w != 0.f);
      *(float4*)&tile[lr*516 + ls*4 + (i << 6)] = v;
    }
    __syncthreads();
    int kbG = (ch << 4) + lr;
    size_t base = (((size_t)blk * 4096) + (size_t)kbG * 64 + (size_t)ls * 4) * 8;
#pragma unroll
    for (int j = 0; j < 4; ++j) {
      int u = ls*4 + j;
      int kg = u >> 4, lc = u & 15;
      int crel = lr*32 + kg*8;
      const float* src = &tile[lc*516 + crel];
      int R = r0 + lc;
      int cg0 = c0 + crel;
      f16x8 wv;
#pragma unroll
      for (int e = 0; e < 8; ++e) {
        float v = src[e];
        bool dg = (cg0 + e) == R;
        wv[e] = (_Float16)(dg ? 1.f : v);
      }
      *(f16x8*)(Aw + base + j*8) = wv;
    }
  }
#pragma unroll
  for (int o = 8; o; o >>= 1) { sum += __shfl_down(sum, o); cnt += __shfl_down(cnt, o); }
  if (ls == 0) {
    int R = r0 + lr;
    float dw = rsqrtf(sum + 1.f), db = rsqrtf((float)cnt + 1.f);
    dinvw[R] = dw; dinvb[R] = db;
    dshw[lr] = dw; dshb[lr] = db;
  }
  __syncthreads();
  {
    int R = r0 + lr, rloc = R & (NN-1);
    float x0 = x[R*3], x1 = x[R*3+1], x2 = x[R*3+2];
#pragma unroll
    for (int e = 0; e < 4; ++e) {
      int c = ls*4 + e;
      int side = c >> 5, cc = c & 31;
      float v = 0.f;
      if (cc < 30) {
        const float* W = Win + side*90;
        v = (x0*W[cc] + x1*W[30+cc] + x2*W[60+cc]) * (side ? dshb[lr] : dshw[lr]);
      }
      HT[fidx(gph*4 + (c >> 4), c & 15, rloc)] = (_Float16)v;
    }
  }
}

// R22: FUSED pair GEMM — one pass over Aw computes BOTH sides (binary A
// derived in-register). 512 blocks x 32 rows; 4 waves = rowhalf x colhalf;
// per kb: 3 loads (af, bw, bb) + binz + 2 MFMAs.
__global__ __launch_bounds__(256, 3) void k_gemm_pair(
    const _Float16* __restrict__ Aw, const _Float16* __restrict__ HT,
    const float* __restrict__ dinvw, const float* __restrict__ dinvb,
    float* __restrict__ Zw, float* __restrict__ Zb,
    float* __restrict__ bktW, float* __restrict__ bktB)
{
  __shared__ float zsW[32][32];
  __shared__ float zsB[32][32];
  int t = threadIdx.x;
  int row0 = blockIdx.x << 5;
  size_t g = (size_t)(row0 >> 11);
  int w = t >> 6, l = t & 63, lc = l & 15, kg = l >> 4;
  int rowhalf = w & 1, colhalf = w >> 1;
  size_t rowblk = g*128 + ((row0 & 2047) >> 4) + rowhalf;
  const _Float16* Af  = Aw + (rowblk * 64) * 512 + l * 8;
  const _Float16* BfW = HT + (((size_t)(g*4 + colhalf)) * 64) * 512 + l * 8;
  const _Float16* BfB = HT + (((size_t)(g*4 + 2 + colhalf)) * 64) * 512 + l * 8;
  f32x4 accW = {0,0,0,0}, accB = {0,0,0,0};
#pragma unroll 8
  for (int kb = 0; kb < 64; ++kb) {
    f16x8 af = *(const f16x8*)(Af  + kb*512);
    f16x8 bw = *(const f16x8*)(BfW + kb*512);
    f16x8 bb = *(const f16x8*)(BfB + kb*512);
    f16x8 ab = binz(af);
    accW = __builtin_amdgcn_mfma_f32_16x16x32_f16(af, bw, accW, 0, 0, 0);
    accB = __builtin_amdgcn_mfma_f32_16x16x32_f16(ab, bb, accB, 0, 0, 0);
  }
#pragma unroll
  for (int i = 0; i < 4; ++i) {
    zsW[rowhalf*16 + kg*4 + i][colhalf*16 + lc] = accW[i];
    zsB[rowhalf*16 + kg*4 + i][colhalf*16 + lc] = accB[i];
  }
  __syncthreads();
  {
    int r = t >> 3, c4 = (t & 7) << 2;
    float dW = dinvw[row0 + r], dB = dinvb[row0 + r];
    float4 oW, oB;
    oW.x = zsW[r][c4+0]*dW; oW.y = zsW[r][c4+1]*dW;
    oW.z = zsW[r][c4+2]*dW; oW.w = zsW[r][c4+3]*dW;
    oB.x = zsB[r][c4+0]*dB; oB.y = zsB[r][c4+1]*dB;
    oB.z = zsB[r][c4+2]*dB; oB.w = zsB[r][c4+3]*dB;
    zsW[r][c4+0]=oW.x; zsW[r][c4+1]=oW.y; zsW[r][c4+2]=oW.z; zsW[r][c4+3]=oW.w;
    zsB[r][c4+0]=oB.x; zsB[r][c4+1]=oB.y; zsB[r][c4+2]=oB.z; zsB[r][c4+3]=oB.w;
    *(float4*)(Zw + (((size_t)(row0 + r)) << 5) + c4) = oW;
    *(float4*)(Zb + (((size_t)(row0 + r)) << 5) + c4) = oB;
  }
  __syncthreads();
  int copy = blockIdx.x & 63;
  if (t < 30) {
    float s1 = 0.f, s2 = 0.f;
    for (int r = 0; r < 32; ++r) { float v = zsW[r][t]; s1 += v; s2 += v*v; }
    atomicAdd(&bktW[(t*64+copy)*2],   s1);
    atomicAdd(&bktW[(t*64+copy)*2+1], s2);
  } else if (t >= 64 && t < 94) {
    int c = t - 64;
    float s1 = 0.f, s2 = 0.f;
    for (int r = 0; r < 32; ++r) { float v = zsB[r][c]; s1 += v; s2 += v*v; }
    atomicAdd(&bktB[(c*64+copy)*2],   s1);
    atomicAdd(&bktB[(c*64+copy)*2+1], s2);
  }
}

// R22: FUSED level-3 GEMM — one Aw pass computes w-side (2 frags) AND b-side
// (7 frags, binary A in-register). 512 blocks x 32 rows; waves = rowhalf x grp
// (grp0: w0,w1 + b0..b2; grp1: b3..b6).
__global__ __launch_bounds__(256, 3) void k_gemm_l3(
    const _Float16* __restrict__ Aw,
    const _Float16* __restrict__ Hw3T, const _Float16* __restrict__ HbT,
    const float* __restrict__ dinvw, const float* __restrict__ dinvb,
    float* __restrict__ Zw, float* __restrict__ Zb,
    float* __restrict__ bktW3, float* __restrict__ bktB3)
{
  __shared__ float zsW[32][32];
  __shared__ float st[200];
  int t = threadIdx.x;
  int w = t >> 6, l = t & 63, lc = l & 15, kg = l >> 4;
  int rowhalf = w & 1, grp = w >> 1;
  int row0 = blockIdx.x << 5;
  size_t g = (size_t)(row0 >> 11);
  size_t rowblk = g*128 + ((row0 & 2047) >> 4) + rowhalf;
  const _Float16* Af = Aw + (rowblk * 64) * 512 + l * 8;
  for (int s = t; s < 200; s += 256) st[s] = 0.f;
  f32x4 accW0 = {0,0,0,0}, accW1 = {0,0,0,0};
  f32x4 accB[4];
#pragma unroll
  for (int f = 0; f < 4; ++f) accB[f] = (f32x4){0,0,0,0};
  if (grp == 0) {
    const _Float16* Bw0 = Hw3T + (((size_t)(g*2)) * 64) * 512 + l * 8;
    const _Float16* Bw1 = Bw0 + (size_t)64 * 512;
    const _Float16* Bb  = HbT + (((size_t)(g*7)) * 64) * 512 + l * 8;
#pragma unroll 4
    for (int kb = 0; kb < 64; ++kb) {
      f16x8 af = *(const f16x8*)(Af + kb*512);
      f16x8 ab = binz(af);
      accW0 = __builtin_amdgcn_mfma_f32_16x16x32_f16(af, *(const f16x8*)(Bw0 + kb*512), accW0, 0, 0, 0);
      accW1 = __builtin_amdgcn_mfma_f32_16x16x32_f16(af, *(const f16x8*)(Bw1 + kb*512), accW1, 0, 0, 0);
      accB[0] = __builtin_amdgcn_mfma_f32_16x16x32_f16(ab, *(const f16x8*)(Bb +           kb*512), accB[0], 0, 0, 0);
      accB[1] = __builtin_amdgcn_mfma_f32_16x16x32_f16(ab, *(const f16x8*)(Bb + 32768  + kb*512), accB[1], 0, 0, 0);
      accB[2] = __builtin_amdgcn_mfma_f32_16x16x32_f16(ab, *(const f16x8*)(Bb + 65536  + kb*512), accB[2], 0, 0, 0);
    }
  } else {
    const _Float16* Bb = HbT + (((size_t)(g*7 + 3)) * 64) * 512 + l * 8;
#pragma unroll 4
    for (int kb = 0; kb < 64; ++kb) {
      f16x8 af = *(const f16x8*)(Af + kb*512);
      f16x8 ab = binz(af);
#pragma unroll
      for (int f = 0; f < 4; ++f) {
        f16x8 bf = *(const f16x8*)(Bb + (size_t)f*32768 + kb*512);
        accB[f] = __builtin_amdgcn_mfma_f32_16x16x32_f16(ab, bf, accB[f], 0, 0, 0);
      }
    }
  }
  if (grp == 0) {
#pragma unroll
    for (int i = 0; i < 4; ++i) {
      zsW[rowhalf*16 + kg*4 + i][lc]      = accW0[i];
      zsW[rowhalf*16 + kg*4 + i][16 + lc] = accW1[i];
    }
  }
  __syncthreads();
  // Zw epilogue (all threads, disjoint cells)
  {
    int r = t >> 3, c4 = (t & 7) << 2;
    float d = dinvw[row0 + r];
    float4 o;
    o.x = zsW[r][c4+0]*d; o.y = zsW[r][c4+1]*d;
    o.z = zsW[r][c4+2]*d; o.w = zsW[r][c4+3]*d;
    zsW[r][c4+0]=o.x; zsW[r][c4+1]=o.y; zsW[r][c4+2]=o.z; zsW[r][c4+3]=o.w;
    *(float4*)(Zw + (((size_t)(row0 + r)) << 5) + c4) = o;
  }
  // b-side direct writes + st atomics (st zeroed pre-loop; flushed after sync)
  {
    float d[4];
#pragma unroll
    for (int i = 0; i < 4; ++i) d[i] = dinvb[row0 + rowhalf*16 + kg*4 + i];
    int fbase = grp ? 3 : 0;
    int nf = grp ? 4 : 3;
    for (int f = 0; f < nf; ++f) {
      int col = (fbase + f)*16 + lc;
#pragma unroll
      for (int i = 0; i < 4; ++i) {
        float v = accB[f][i] * d[i];
        int row = row0 + rowhalf*16 + kg*4 + i;
        if (col < 104) Zb[(size_t)row * 104 + col] = v;
        if (col < 100) { atomicAdd(&st[col*2], v); atomicAdd(&st[col*2+1], v*v); }
      }
    }
  }
  __syncthreads();
  int copy = blockIdx.x & 7;
  if (t < 30) {
    float s1 = 0.f, s2 = 0.f;
    for (int r = 0; r < 32; ++r) { float v = zsW[r][t]; s1 += v; s2 += v*v; }
    atomicAdd(&bktW3[(t*8+copy)*2],   s1);
    atomicAdd(&bktW3[(t*8+copy)*2+1], s2);
  }
  for (int i2 = t; i2 < 200; i2 += 256)
    atomicAdd(&bktB3[((i2>>1)*8 + copy)*2 + (i2&1)], st[i2]);
}

// R20: frag-major As = adj @ S = A_w @ S - S. 512 blocks of 32 rows,
// waves = rowhalf x fraggroup.
__global__ __launch_bounds__(256, 3) void k_gemm_as(
    const _Float16* __restrict__ Aw, const _Float16* __restrict__ ST,
    const unsigned short* __restrict__ Srow, float* __restrict__ As)
{
  int t = threadIdx.x;
  int w = t >> 6, l = t & 63, lc = l & 15, kg = l >> 4;
  int row0 = blockIdx.x << 5;
  size_t g = (size_t)(row0 >> 11);
  int rowhalf = w & 1, fgrp = w >> 1;
  size_t rowblk = g*128 + ((row0 & 2047) >> 4) + rowhalf;
  const _Float16* Af = Aw + (rowblk * 64) * 512 + l * 8;
  int f0 = fgrp * 4, nf = fgrp ? 3 : 4;
  const _Float16* Bf = ST + (((size_t)(g*7 + f0)) * 64) * 512 + l * 8;
  f32x4 acc[4];
#pragma unroll
  for (int f = 0; f < 4; ++f) acc[f] = (f32x4){0,0,0,0};
  if (nf == 4) {
#pragma unroll 8
    for (int kb = 0; kb < 64; ++kb) {
      f16x8 af = *(const f16x8*)(Af + kb*512);
#pragma unroll
      for (int f = 0; f < 4; ++f) {
        f16x8 bf = *(const f16x8*)(Bf + (size_t)f*32768 + kb*512);
        acc[f] = __builtin_amdgcn_mfma_f32_16x16x32_f16(af, bf, acc[f], 0, 0, 0);
      }
    }
  } else {
#pragma unroll 8
    for (int kb = 0; kb < 64; ++kb) {
      f16x8 af = *(const f16x8*)(Af + kb*512);
#pragma unroll
      for (int f = 0; f < 3; ++f) {
        f16x8 bf = *(const f16x8*)(Bf + (size_t)f*32768 + kb*512);
        acc[f] = __builtin_amdgcn_mfma_f32_16x16x32_f16(af, bf, acc[f], 0, 0, 0);
      }
    }
  }
  for (int f = 0; f < nf; ++f) {
    int col = (f0 + f)*16 + lc;
#pragma unroll
    for (int i = 0; i < 4; ++i) {
      int row = row0 + rowhalf*16 + kg*4 + i;
      if (col < 104)
        As[(size_t)row * 104 + col] = acc[f][i] - h2f(Srow[(size_t)row * 104 + col]);
    }
  }
}

// apply BN (inline bucket reduce) -> store x/s -> next-layer weight GEMM ->
// fp16 frag-major H outputs.
template<int LEVEL>
__global__ __launch_bounds__(256) void k_apply_gemm(
    const float* __restrict__ Zw, const float* __restrict__ bktW,
    const float* __restrict__ gW, const float* __restrict__ beW,
    float* __restrict__ xst, const float* __restrict__ Ww,
    const float* __restrict__ dinvw,
    const float* __restrict__ Zb, const float* __restrict__ bktB,
    const float* __restrict__ gB, const float* __restrict__ beB,
    float* __restrict__ sst, const float* __restrict__ Wb,
    const float* __restrict__ dinvb,
    _Float16* __restrict__ HwOutT, _Float16* __restrict__ HbOutT)
{
  constexpr int NGB = (LEVEL == 1) ? 8 : 26;
  constexpr int OSTRIDEB = (LEVEL == 1) ? 32 : 104;
  constexpr int NG = 8 + NGB;
  __shared__ float WwL[30*32];
  __shared__ float WbL[30*OSTRIDEB];
  __shared__ float awL[60], abL[60];
  int t = threadIdx.x;
  if (t < 60) {
    int c = t % 30;
    bool isW = t < 30;
    const float4* p = (const float4*)((isW ? bktW : bktB) + c*128);
    float s1 = 0.f, s2 = 0.f;
#pragma unroll
    for (int k = 0; k < 32; ++k) { float4 v = p[k]; s1 += v.x + v.z; s2 += v.y + v.w; }
    float mean = s1/16384.f, var = s2/16384.f - mean*mean, inv = rsqrtf(var + 1e-5f);
    float aa = (isW ? gW : gB)[c]*inv;
    float* dst = isW ? awL : abL;
    dst[c] = aa; dst[30+c] = (isW ? beW : beB)[c] - mean*aa;
  }
  for (int idx = t; idx < 30*32; idx += 256) {
    int k = idx >> 5, c = idx & 31;
    WwL[idx] = (c < 30) ? Ww[k*30 + c] : 0.f;
  }
  if (LEVEL == 1) {
    for (int idx = t; idx < 30*32; idx += 256) {
      int k = idx >> 5, c = idx & 31;
      WbL[idx] = (c < 30) ? Wb[k*30 + c] : 0.f;
    }
  } else {
    for (int idx = t; idx < 30*OSTRIDEB; idx += 256) {
      int k = idx / OSTRIDEB, j = idx % OSTRIDEB;
      WbL[idx] = (j < 100) ? Wb[k*100 + j] : 0.f;
    }
  }
  __syncthreads();
  int gid = blockIdx.x * 256 + t;
  int row = gid / NG, g = gid % NG;
  size_t gph = (size_t)(row >> 11);
  int rloc = row & (NN-1);
  if (g < 8) {
    const float4* Z4 = (const float4*)Zw + (size_t)row*8;
    float4 z4[8];
#pragma unroll
    for (int u = 0; u < 8; ++u) z4[u] = Z4[u];
    const float* z = (const float*)z4;
    int ch = 4*g;
    float4 zg = Z4[g];
    float4 xv;
    xv.x = (ch+0 < 30) ? awL[ch+0]*zg.x + awL[30+ch+0] : 0.f;
    xv.y = (ch+1 < 30) ? awL[ch+1]*zg.y + awL[30+ch+1] : 0.f;
    xv.z = (ch+2 < 30) ? awL[ch+2]*zg.z + awL[30+ch+2] : 0.f;
    xv.w = (ch+3 < 30) ? awL[ch+3]*zg.w + awL[30+ch+3] : 0.f;
    ((float4*)xst)[(size_t)row*8+g] = xv;
    float4 o = {0,0,0,0};
#pragma unroll
    for (int k = 0; k < 30; ++k) {
      float xk = awL[k]*z[k] + awL[30+k];
      float4 w = *(const float4*)(WwL + k*32 + 4*g);
      FMA4(o, xk, w);
    }
    float d = dinvw[row];
    float ov[4] = {d*o.x, d*o.y, d*o.z, d*o.w};
#pragma unroll
    for (int i = 0; i < 4; ++i) {
      int col = ch + i;
      if (LEVEL == 1) HwOutT[fidx(gph*4 + (col>>4), col & 15, rloc)] = (_Float16)ov[i];
      else            HwOutT[fidx(gph*2 + (col>>4), col & 15, rloc)] = (_Float16)ov[i];
    }
  } else {
    int gb = g - 8;
    const float4* Z4 = (const float4*)Zb + (size_t)row*8;
    float4 z4[8];
#pragma unroll
    for (int u = 0; u < 8; ++u) z4[u] = Z4[u];
    const float* z = (const float*)z4;
    if (gb < 8) {
      int ch = 4*gb;
      float4 zg = Z4[gb];
      float4 sv;
      sv.x = (ch+0 < 30) ? abL[ch+0]*zg.x + abL[30+ch+0] : 0.f;
      sv.y = (ch+1 < 30) ? abL[ch+1]*zg.y + abL[30+ch+1] : 0.f;
      sv.z = (ch+2 < 30) ? abL[ch+2]*zg.z + abL[30+ch+2] : 0.f;
      sv.w = (ch+3 < 30) ? abL[ch+3]*zg.w + abL[30+ch+3] : 0.f;
      ((float4*)sst)[(size_t)row*8+gb] = sv;
    }
    float4 o = {0,0,0,0};
#pragma unroll
    for (int k = 0; k < 30; ++k) {
      float sk = abL[k]*z[k] + abL[30+k];
      float4 w = *(const float4*)(WbL + k*OSTRIDEB + 4*gb);
      FMA4(o, sk, w);
    }
    float d = dinvb[row];
    float ov[4] = {d*o.x, d*o.y, d*o.z, d*o.w};
#pragma unroll
    for (int i = 0; i < 4; ++i) {
      int col = 4*gb + i;
      if (LEVEL == 1) { int c2 = 32 + col; HbOutT[fidx(gph*4 + (c2>>4), c2 & 15, rloc)] = (_Float16)ov[i]; }
      else            HbOutT[fidx(gph*7 + (col>>4), col & 15, rloc)] = (_Float16)ov[i];
    }
    if (LEVEL == 2) {
      if (gb == 24) {
#pragma unroll
        for (int c = 104; c < 108; ++c) HbOutT[fidx(gph*7 + 6, c & 15, rloc)] = (_Float16)0.f;
      } else if (gb == 25) {
#pragma unroll
        for (int c = 108; c < 112; ++c) HbOutT[fidx(gph*7 + 6, c & 15, rloc)] = (_Float16)0.f;
      }
    }
  }
}

// fcpool with inline L3 finalize + fused softmax -> S row-major [row][104] AND
// frag-major S^T (B-operand for the As GEMM; pad cols zeroed).
__global__ __launch_bounds__(256) void k_fcpool(
    const float* __restrict__ Zw3, const float* __restrict__ bktW3,
    const float* __restrict__ gW3, const float* __restrict__ beW3,
    const float* __restrict__ Zb3, const float* __restrict__ bktB3,
    const float* __restrict__ g100, const float* __restrict__ be100,
    const float* __restrict__ s11, const float* __restrict__ s12,
    const float* __restrict__ Wfc, const float* __restrict__ bfc,
    float* __restrict__ x13, unsigned short* __restrict__ Srow,
    _Float16* __restrict__ ST)
{
  __shared__ float shm[14240];   // feat 64x160 = 10240 | Wl 40x100 = 4000
  __shared__ float aw3[60], ab3[200];
  float* feat = shm;
  float* Wl = shm + 10240;
  int t = threadIdx.x;
  int g0 = blockIdx.x * 64;
  size_t gph = (size_t)(g0 >> 11);
  if (t < 30) {
    const float4* p = (const float4*)(bktW3 + t*16);
    float s1 = 0.f, s2 = 0.f;
#pragma unroll
    for (int k = 0; k < 4; ++k) { float4 v = p[k]; s1 += v.x + v.z; s2 += v.y + v.w; }
    float mean = s1/16384.f, var = s2/16384.f - mean*mean, inv = rsqrtf(var + 1e-5f);
    float aa = gW3[t]*inv; aw3[t] = aa; aw3[30+t] = beW3[t] - mean*aa;
  } else if (t >= 64 && t < 164) {
    int c = t - 64;
    const float4* p = (const float4*)(bktB3 + c*16);
    float s1 = 0.f, s2 = 0.f;
#pragma unroll
    for (int k = 0; k < 4; ++k) { float4 v = p[k]; s1 += v.x + v.z; s2 += v.y + v.w; }
    float mean = s1/16384.f, var = s2/16384.f - mean*mean, inv = rsqrtf(var + 1e-5f);
    float aa = g100[c]*inv; ab3[c] = aa; ab3[100+c] = be100[c] - mean*aa;
  }
  __syncthreads();
  for (int idx = t; idx < 64*160; idx += 256) {
    int l = idx / 160, c = idx % 160;
    int g = g0 + l;
    float v;
    if (c < 30) v = s11[(size_t)g*32 + c];
    else if (c < 60) v = s12[(size_t)g*32 + (c-30)];
    else { int k = c - 60; v = ab3[k]*Zb3[(size_t)g*104 + k] + ab3[100 + k]; }
    feat[l*160 + c] = v;
  }
  for (int idx = t; idx < 64*32; idx += 256) {
    int l = idx >> 5, c = idx & 31;
    int g = g0 + l;
    x13[(size_t)g*32+c] = (c < 30) ? aw3[c]*Zw3[(size_t)g*32+c] + aw3[30+c] : 0.f;
  }
  int np = t >> 3, kg = t & 7;
  int n0 = np*2, n1 = np*2 + 1;
  int kbase = kg*12 + (kg < 4 ? kg : 4);
  int klen  = kg < 4 ? 13 : 12;
  float a0[13], a1[13];
#pragma unroll
  for (int j = 0; j < 13; ++j) { a0[j] = 0.f; a1[j] = 0.f; }
  for (int ch = 0; ch < 4; ++ch) {
    __syncthreads();
    for (int idx = t; idx < 4000; idx += 256) {
      int r = idx/100, j = idx%100;
      Wl[r*100 + j] = Wfc[(ch*40 + r)*100 + j];
    }
    __syncthreads();
    for (int kk = 0; kk < 40; ++kk) {
      float f0 = feat[n0*160 + ch*40+kk];
      float f1 = feat[n1*160 + ch*40+kk];
#pragma unroll
      for (int j = 0; j < 13; ++j) {
        if (j < klen) {
          float w = Wl[kk*100 + kbase + j];
          a0[j] += f0*w; a1[j] += f1*w;
        }
      }
    }
  }
  __syncthreads();
  float* sRow = shm;  // reuse as [64][100]
  for (int j = 0; j < klen; ++j) {
    int k = kbase + j;
    sRow[n0*100 + k] = a0[j] + bfc[k];
    sRow[n1*100 + k] = a1[j] + bfc[k];
  }
  __syncthreads();
  int n = t >> 2, part = t & 3;
  int i0 = part*25;
  int rloc = (g0 + n) & (NN-1);
  float m = -3.4e38f;
  for (int i = 0; i < 25; ++i) m = fmaxf(m, sRow[n*100 + i0 + i]);
  m = fmaxf(m, __shfl_xor(m, 1));
  m = fmaxf(m, __shfl_xor(m, 2));
  float ev[25]; float s = 0.f;
  for (int i = 0; i < 25; ++i) { float e = __expf(sRow[n*100 + i0 + i] - m); ev[i] = e; s += e; }
  s += __shfl_xor(s, 1);
  s += __shfl_xor(s, 2);
  float rinv = 1.f / s;
  for (int i = 0; i < 25; ++i) {
    float v = ev[i] * rinv;
    int c = i0 + i;
    Srow[(size_t)(g0+n)*104 + c] = f2h(v);
    ST[fidx(gph*7 + (c>>4), c & 15, rloc)] = (_Float16)v;
  }
  if (part == 3) {
#pragma unroll
    for (int c = 100; c < 104; ++c) Srow[(size_t)(g0+n)*104 + c] = 0;
#pragma unroll
    for (int c = 100; c < 112; ++c) ST[fidx(gph*7 + (c>>4), c & 15, rloc)] = (_Float16)0.f;
  }
}

// pooled partials + FUSED stage-1 column max (256 blocks, one 64-row tile each).
__global__ __launch_bounds__(256) void k_pool_part(
    const unsigned short* __restrict__ S, const float* __restrict__ x13,
    const float* __restrict__ As, const float* __restrict__ x11,
    const float* __restrict__ x12, float* __restrict__ pp, float* __restrict__ pm)
{
  __shared__ float sL[64][100];
  __shared__ float xL[64][132];
  __shared__ float red[256];
  int t = threadIdx.x;
  int b = blockIdx.x >> 5, chunk = blockIdx.x & 31;
  int g0 = b * 2048 + chunk * 64;
  int kt = t/10, dt = t%10;
  int k0 = kt*4, d0 = dt*13;
  float acc[4][13];
#pragma unroll
  for (int a = 0; a < 4; ++a)
#pragma unroll
    for (int j = 0; j < 13; ++j) acc[a][j] = 0.f;
  for (int idx = t; idx < 64*100; idx += 256) {
    int l = idx/100, k = idx%100;
    sL[l][k] = h2f(S[(size_t)(g0+l)*104 + k]);
  }
  for (int idx = t; idx < 64*130; idx += 256) {
    int l = idx/130, d = idx%130;
    xL[l][d] = d < 30 ? x13[(size_t)(g0+l)*32 + d] : As[(size_t)(g0+l)*104 + (d-30)];
  }
  __syncthreads();
  if (t < 250) {
    for (int kk = 0; kk < 64; ++kk) {
      float sv[4];
#pragma unroll
      for (int a = 0; a < 4; ++a) sv[a] = sL[kk][k0+a];
#pragma unroll
      for (int j = 0; j < 13; ++j) {
        float xv = xL[kk][d0+j];
#pragma unroll
        for (int a = 0; a < 4; ++a) acc[a][j] += sv[a]*xv;
      }
    }
    float* dst = pp + (size_t)blockIdx.x * 13000;
    for (int a = 0; a < 4; ++a)
      for (int j = 0; j < 13; ++j)
        dst[(k0+a)*130 + (d0+j)] = acc[a][j];
  }
  __syncthreads();
  {
    int c = t & 31, rg = t >> 5;
    const float* srcs[3] = {x11, x12, x13};
#pragma unroll
    for (int a = 0; a < 3; ++a) {
      const float* p = srcs[a] + (size_t)(g0+rg)*32 + c;
      float m = -3.4e38f;
#pragma unroll
      for (int it = 0; it < 8; ++it) m = fmaxf(m, p[it*256]);
      red[t] = m;
      __syncthreads();
      if (t < 30) {
        float mm = red[t];
        for (int g = 1; g < 8; ++g) mm = fmaxf(mm, red[g*32+t]);
        pm[(size_t)blockIdx.x*90 + a*30 + t] = mm;
      }
      __syncthreads();
    }
  }
}

// full-GPU reduction of the 32 pool partials per graph -> ppool[8][13000].
__global__ __launch_bounds__(256) void k_pool_reduce(
    const float* __restrict__ pp, float* __restrict__ ppool)
{
  int b = blockIdx.x / 51, blk = blockIdx.x % 51;
  int idx = blk * 256 + threadIdx.x;
  if (idx < 13000) {
    const float* src = pp + (size_t)b * 32 * 13000 + idx;
    float s = 0.f;
#pragma unroll
    for (int c = 0; c < 32; ++c) s += src[c*13000];
    ppool[(size_t)b*13000 + idx] = s;
  }
}

// Fully fused stage 2 (register-tiled, fp32 A2 in LDS).
__global__ __launch_bounds__(256) void k_s2fused(
    const float* __restrict__ ppool, const float* __restrict__ partmax,
    const float* __restrict__ Wm,    // 3 consecutive 30x30
    const float* __restrict__ g30,   // +150
    const float* __restrict__ be30,  // +150
    float* __restrict__ bktS2,       // [3][30][2] (zeroed)
    int* __restrict__ cnt,           // zeroed barrier counter
    const float* __restrict__ W1, const float* __restrict__ b1,
    const float* __restrict__ W2, const float* __restrict__ b2,
    float* __restrict__ out)
{
  __shared__ float A2f[10000];     // 40 KB, fp32
  __shared__ float buf1[3000];     // X (stride 30)
  __shared__ float buf2[3200];     // T padded [100][32]
  __shared__ float WL[960];        // W padded [30][32]
  __shared__ float dl[100];
  __shared__ float st1[30], st2[30];
  __shared__ float coef[60];
  __shared__ float x1L[90], x2L[90], hh[50];
  int b = blockIdx.x, t = threadIdx.x;
  for (int idx = t; idx < 13000; idx += 256) {
    float s = ppool[(size_t)b*13000 + idx];
    int k = idx/130, d = idx%130;
    if (d < 30) buf1[k*30 + d] = s;
    else A2f[k*100 + (d-30)] = s;
  }
  __syncthreads();
  if (t < 100 && A2f[t*101] == 0.f) A2f[t*101] = 1.f;
  __syncthreads();
  if (t < 100) {
    float s = 0.f;
    for (int j = 0; j < 100; ++j) s += A2f[t*100 + j];
    dl[t] = s > 0.f ? rsqrtf(s) : 0.f;
  }
  __syncthreads();
  for (int idx = t; idx < 10000; idx += 256) {
    int i = idx/100, j = idx%100;
    A2f[idx] = dl[i]*dl[j]*A2f[idx];
  }
  int rp = t >> 2, cg = t & 3;
  int i0 = rp*2, c0 = cg*8;
  bool act = (t < 200);
  for (int L = 0; L < 3; ++L) {
    if (t < 30) { st1[t] = 0.f; st2[t] = 0.f; }
    const float* W = Wm + L*900;
    for (int idx = t; idx < 960; idx += 256) {
      int k = idx >> 5, c = idx & 31;
      WL[idx] = (c < 30) ? W[k*30 + c] : 0.f;
    }
    __syncthreads();
    if (act) {
      float a0[8] = {0,0,0,0,0,0,0,0}, a1[8] = {0,0,0,0,0,0,0,0};
      for (int k = 0; k < 30; ++k) {
        float xx0 = buf1[i0*30 + k], xx1 = buf1[(i0+1)*30 + k];
        float4 w0 = *(const float4*)&WL[k*32 + c0];
        float4 w1 = *(const float4*)&WL[k*32 + c0 + 4];
        a0[0] += xx0*w0.x; a0[1] += xx0*w0.y; a0[2] += xx0*w0.z; a0[3] += xx0*w0.w;
        a0[4] += xx0*w1.x; a0[5] += xx0*w1.y; a0[6] += xx0*w1.z; a0[7] += xx0*w1.w;
        a1[0] += xx1*w0.x; a1[1] += xx1*w0.y; a1[2] += xx1*w0.z; a1[3] += xx1*w0.w;
        a1[4] += xx1*w1.x; a1[5] += xx1*w1.y; a1[6] += xx1*w1.z; a1[7] += xx1*w1.w;
      }
      float4 s00 = {a0[0],a0[1],a0[2],a0[3]}, s01 = {a0[4],a0[5],a0[6],a0[7]};
      float4 s10 = {a1[0],a1[1],a1[2],a1[3]}, s11v = {a1[4],a1[5],a1[6],a1[7]};
      *(float4*)&buf2[i0*32 + c0]       = s00;
      *(float4*)&buf2[i0*32 + c0 + 4]   = s01;
      *(float4*)&buf2[(i0+1)*32 + c0]   = s10;
      *(float4*)&buf2[(i0+1)*32 + c0+4] = s11v;
    }
    __syncthreads();
    if (act) {
      float z0[8] = {0,0,0,0,0,0,0,0}, z1[8] = {0,0,0,0,0,0,0,0};
      for (int j = 0; j < 100; ++j) {
        float av0 = A2f[i0*100 + j], av1 = A2f[(i0+1)*100 + j];
        float4 t0 = *(const float4*)&buf2[j*32 + c0];
        float4 t1 = *(const float4*)&buf2[j*32 + c0 + 4];
        z0[0] += av0*t0.x; z0[1] += av0*t0.y; z0[2] += av0*t0.z; z0[3] += av0*t0.w;
        z0[4] += av0*t1.x; z0[5] += av0*t1.y; z0[6] += av0*t1.z; z0[7] += av0*t1.w;
        z1[0] += av1*t0.x; z1[1] += av1*t0.y; z1[2] += av1*t0.z; z1[3] += av1*t0.w;
        z1[4] += av1*t1.x; z1[5] += av1*t1.y; z1[6] += av1*t1.z; z1[7] += av1*t1.w;
      }
#pragma unroll
      for (int k = 0; k < 8; ++k) {
        int c = c0 + k;
        if (c < 30) {
          buf1[i0*30 + c]     = z0[k];
          buf1[(i0+1)*30 + c] = z1[k];
          atomicAdd(&st1[c], z0[k] + z1[k]);
          atomicAdd(&st2[c], z0[k]*z0[k] + z1[k]*z1[k]);
        }
      }
    }
    __syncthreads();
    if (t < 30) {
      atomicAdd(&bktS2[(L*30+t)*2],   st1[t]);
      atomicAdd(&bktS2[(L*30+t)*2+1], st2[t]);
    }
    __syncthreads();
    if (t == 0) {
      __threadfence();
      atomicAdd(cnt, 1);
      while (atomicAdd(cnt, 0) < (L+1)*8) {}
      __threadfence();
    }
    __syncthreads();
    if (t < 30) {
      float s1 = atomicAdd(&bktS2[(L*30+t)*2],   0.f);
      float s2 = atomicAdd(&bktS2[(L*30+t)*2+1], 0.f);
      float mean = s1/800.f, var = s2/800.f - mean*mean, inv = rsqrtf(var + 1e-5f);
      float aa = g30[L*30+t]*inv;
      coef[t] = aa; coef[30+t] = be30[L*30+t] - mean*aa;
    }
    __syncthreads();
    if (L < 2) {
      for (int idx = t; idx < 3000; idx += 256) {
        int c = idx % 30;
        buf1[idx] = coef[c]*buf1[idx] + coef[30+c];
      }
      __syncthreads();
      if (t < 30) {
        float m = -3.4e38f;
        for (int i = 0; i < 100; ++i) m = fmaxf(m, buf1[i*30+t]);
        x2L[L*30+t] = m;
      }
      __syncthreads();
    } else {
      if (t < 30) {
        float m = -3.4e38f;
        for (int i = 0; i < 100; ++i) m = fmaxf(m, coef[t]*buf1[i*30+t] + coef[30+t]);
        x2L[60+t] = m;
      }
    }
  }
  if (t < 90) {
    float m = -3.4e38f;
    for (int s = 0; s < 32; ++s) m = fmaxf(m, partmax[(size_t)(b*32+s)*90 + t]);
    x1L[t] = m;
  }
  __syncthreads();
  if (t < 50) {
    float a = b1[t];
    for (int k = 0; k < 90; ++k) a += x1L[k]*W1[k*50+t];
    for (int k = 0; k < 90; ++k) a += x2L[k]*W1[(90+k)*50+t];
    hh[t] = fmaxf(a, 0.f);
  }
  __syncthreads();
  if (t < 6) {
    float a = b2[t];
    for (int j = 0; j < 50; ++j) a += hh[j]*W2[j*6+t];
    out[b*6+t] = a;
  }
}

// ---------------- launcher ----------------
extern "C" void kernel_launch(void* const* d_in, const int* in_sizes, int n_in,
                              void* d_out, int out_size, void* d_ws, size_t ws_size,
                              hipStream_t stream)
{
  const float* x    = (const float*)d_in[0];
  const float* adj  = (const float*)d_in[1];
  const float* Win  = (const float*)d_in[2];
  const float* W3030= (const float*)d_in[3];
  const float* Wp13 = (const float*)d_in[4];
  // d_in[5]=b30, d_in[6]=b100: cancel through training-mode BN -> unused
  const float* Wfc  = (const float*)d_in[7];
  const float* bfc  = (const float*)d_in[8];
  const float* W1   = (const float*)d_in[9];
  const float* b1   = (const float*)d_in[10];
  const float* W2   = (const float*)d_in[11];
  const float* b2   = (const float*)d_in[12];
  const float* g30  = (const float*)d_in[13];
  const float* be30 = (const float*)d_in[14];
  const float* g100 = (const float*)d_in[15];
  const float* be100= (const float*)d_in[16];
  float* out = (float*)d_out;

  float* wsf = (float*)d_ws;
  float* bL1W = wsf + OF_B1W;  float* bL1B = wsf + OF_B1B;
  float* bL2W = wsf + OF_B2W;  float* bL2B = wsf + OF_B2B;
  float* bL3W = wsf + OF_B3W;  float* bL3B = wsf + OF_B3B;
  float* bktS2 = wsf + OF_S2;
  int*   cnt  = (int*)(wsf + OF_CNT);
  float* dinvw = wsf + OF_DINVW;
  float* dinvb = wsf + OF_DINVB;
  _Float16* HwbT = (_Float16*)(wsf + OF_HWBT);
  _Float16* Hw3T = (_Float16*)(wsf + OF_HW3T);
  _Float16* HbT  = (_Float16*)(wsf + OF_HBT);   // S^T reuses (dead after l3)
  float* Zw = wsf + OF_ZW;
  float* Zb = wsf + OF_ZB;         // stride 104; later reused as As
  float* x11 = wsf + OF_X11;
  float* x12 = wsf + OF_X12;
  float* x13 = wsf + OF_X13;
  float* s11 = wsf + OF_S11;
  float* s12 = wsf + OF_S12;
  float* pp  = wsf + OF_PP;        // [256][13000] pool partials
  float* ppool = wsf + OF_PPOOL;   // [8][13000] reduced
  float* partmax = wsf + OF_PARTMAX; // [256][90]
  _Float16* Aw = (_Float16*)(wsf + OF_AW);
  unsigned short* Srow = (unsigned short*)(wsf + OF_SROW);

  // 11 dispatches
  k_build<<<1024, 256, 0, stream>>>(adj, x, Win, Aw, dinvw, dinvb, HwbT, wsf);

  k_gemm_pair<<<512, 256, 0, stream>>>(Aw, HwbT, dinvw, dinvb, Zw, Zb, bL1W, bL1B);
  k_apply_gemm<1><<<1024, 256, 0, stream>>>(Zw, bL1W, g30+0, be30+0, x11, W3030+0, dinvw,
                                            Zb, bL1B, g30+90, be30+90, s11, W3030+2*900, dinvb, HwbT, HwbT);

  k_gemm_pair<<<512, 256, 0, stream>>>(Aw, HwbT, dinvw, dinvb, Zw, Zb, bL2W, bL2B);
  k_apply_gemm<2><<<2176, 256, 0, stream>>>(Zw, bL2W, g30+30, be30+30, x12, W3030+900, dinvw,
                                            Zb, bL2B, g30+120, be30+120, s12, Wp13, dinvb, Hw3T, HbT);

  k_gemm_l3<<<512, 256, 0, stream>>>(Aw, Hw3T, HbT, dinvw, dinvb, Zw, Zb, bL3W, bL3B);
  k_fcpool<<<256, 256, 0, stream>>>(Zw, bL3W, g30+60, be30+60, Zb, bL3B, g100, be100,
                                    s11, s12, Wfc, bfc, x13, Srow, HbT /* S^T */);

  k_gemm_as<<<512, 256, 0, stream>>>(Aw, HbT /* S^T */, Srow, Zb /* As */);
  k_pool_part<<<256, 256, 0, stream>>>(Srow, x13, Zb, x11, x12, pp, partmax);
  k_pool_reduce<<<408, 256, 0, stream>>>(pp, ppool);

  k_s2fused<<<BATCH, 256, 0, stream>>>(ppool, partmax, W3030+3*900, g30+150, be30+150,
                                       bktS2, cnt, W1, b1, W2, b2, out);
}